// Round 8
// baseline (86.252 us; speedup 1.0000x reference)
//
#include <hip/hip_runtime.h>
#include <math.h>

#define DM 512
#define LSEQ 8192
#define NV 8
#define TOK 1608
#define BROWS 32     // patch rows per block
#define NTHR 256     // 4 waves; wave = 8 rows x 512 cols; thread = 8r x 8c

typedef _Float16 h2 __attribute__((ext_vector_type(2)));
typedef float f4n __attribute__((ext_vector_type(4)));   // native float4 for builtins

// Heavy-first segment order (pl=128 first). seg -> v: {6,7,4,5,2,3,0,1}
__device__ __constant__ int c_segv[8]   = {6, 7, 4, 5, 2, 3, 0, 1};
// blocks/seg = 32 batches * (n_p/32): 32,32,128,128,128,128,512,512
__device__ __constant__ int c_cum[9]    = {0, 32, 64, 192, 320, 448, 576, 1088, 1600};
__device__ __constant__ int c_lgch[8]   = {0, 0, 2, 2, 2, 2, 4, 4};   // log2(chunks/batch)
// indexed by v:
__device__ __constant__ int c_tokoff[8] = {0, 513, 1026, 1155, 1284, 1413, 1542, 1575};
__device__ __constant__ int c_np[8]     = {512, 512, 128, 128, 128, 128, 32, 32};
// packed-half2-weight word offsets within d_ws per v; pe occupies words [0,262144)
__device__ __constant__ int c_wtoff[8]  = {262144, 262144, 266240, 266240,
                                           274432, 274432, 290816, 290816};

__device__ __forceinline__ float fdot2f(h2 a, h2 b, float c) {
#if __has_builtin(__builtin_amdgcn_fdot2)
    return __builtin_amdgcn_fdot2(a, b, c, false);
#else
    return fmaf((float)a.y, (float)b.y, fmaf((float)a.x, (float)b.x, c));
#endif
}
__device__ __forceinline__ h2 bch2(unsigned u) { return __builtin_bit_cast(h2, u); }

__device__ __forceinline__ void nt_store4(float* p, float4 v) {
#if __has_builtin(__builtin_nontemporal_store)
    f4n t; t.x = v.x; t.y = v.y; t.z = v.z; t.w = v.w;
    __builtin_nontemporal_store(t, reinterpret_cast<f4n*>(p));
#else
    *reinterpret_cast<float4*>(p) = v;
#endif
}

// ---------------------------------------------------------------------------
// Setup: blocks [0,512) build pe[512][512] fp32 (numpy-matched sinusoidal);
// blocks [512,632) pack transposed fp16 weights wt_h[k2][512] (half2 words).
// ---------------------------------------------------------------------------
__global__ __launch_bounds__(512) void setup_kernel(
    const float* __restrict__ w16, const float* __restrict__ w32,
    const float* __restrict__ w64, const float* __restrict__ w128,
    float* __restrict__ ws)
{
    int bid = blockIdx.x;
    int d = threadIdx.x;
    if (bid < 512) {
        int idx = bid * 512 + d;
        int i = idx >> 9;
        int dd = idx & (DM - 1);
        const float c = -9.210340371976184f / 512.0f;  // -ln(10000)/D
        float div = expf((float)(dd & ~1) * c);
        float ang = (float)i * div;
        ws[idx] = (dd & 1) ? cosf(ang) : sinf(ang);
        return;
    }
    int j = bid - 512;                 // 120 half2-rows across the 4 matrices
    const float* w; int pl, k2, off;
    if (j < 8)       { w = w16;  pl = 16;  k2 = j;      off = 262144; }
    else if (j < 24) { w = w32;  pl = 32;  k2 = j - 8;  off = 266240; }
    else if (j < 56) { w = w64;  pl = 64;  k2 = j - 24; off = 274432; }
    else             { w = w128; pl = 128; k2 = j - 56; off = 290816; }
    float2 p = *reinterpret_cast<const float2*>(w + (size_t)d * pl + 2 * k2);
    h2 h; h.x = (_Float16)p.x; h.y = (_Float16)p.y;
    reinterpret_cast<unsigned*>(ws)[off + k2 * DM + d] = __builtin_bit_cast(unsigned, h);
}

// ---------------------------------------------------------------------------
// Per-variable block body. 8 rows x 8 cols per thread; 8-k iterations with
// W prefetched one full iteration (~512 VALU cyc) ahead; b128 LDS broadcasts.
// ---------------------------------------------------------------------------
template<int PL, int SF>
__device__ __forceinline__ void patch_block(
    const float* __restrict__ x, unsigned* __restrict__ ldsu,
    const float* __restrict__ bias, const float* __restrict__ chan,
    const float* __restrict__ ws, float* __restrict__ out,
    int v, int b, int i0, int tokoff)
{
    constexpr int PL2 = PL >> 1;       // half2 words per row
    constexpr int NK8 = PL >> 3;       // 8-k iterations
    const int tid = threadIdx.x;

    // ---- stage 32 packed patches into LDS as half2 (sampling folded) ----
    constexpr int NE2 = (BROWS * PL) >> 1;   // half2 words total
    const float* xb = x + ((size_t)b * NV + v) * LSEQ + (size_t)i0 * (PL * SF);
    if (SF == 1) {
#pragma unroll
        for (int t = tid; t < (NE2 >> 1); t += NTHR) {   // t = one float4 = 2 words
            float4 q = *reinterpret_cast<const float4*>(xb + 4 * t);
            h2 a; a.x = (_Float16)q.x; a.y = (_Float16)q.y;
            h2 c; c.x = (_Float16)q.z; c.y = (_Float16)q.w;
            uint2 o; o.x = __builtin_bit_cast(unsigned, a);
            o.y = __builtin_bit_cast(unsigned, c);
            *reinterpret_cast<uint2*>(ldsu + 2 * t) = o;
        }
    } else {
#pragma unroll
        for (int p = tid; p < NE2; p += NTHR) {          // one word per float4
            float4 q = *reinterpret_cast<const float4*>(xb + 4 * p);
            h2 a; a.x = (_Float16)q.x; a.y = (_Float16)q.z;
            ldsu[p] = __builtin_bit_cast(unsigned, a);
        }
    }
    __syncthreads();

    // ---- per-thread geometry ----
    const int lane = tid & 63;
    const int wv   = tid >> 6;                   // wave -> rows [8wv, 8wv+8)
    const int c0   = lane << 3;                  // 8 consecutive cols
    const unsigned* prow = ldsu + (wv * 8) * PL2;
    const unsigned* wtv  = reinterpret_cast<const unsigned*>(ws) + c_wtoff[v];

    float acc[8][8];
#pragma unroll
    for (int r = 0; r < 8; ++r)
#pragma unroll
        for (int c = 0; c < 8; ++c) acc[r][c] = 0.f;

    // wc[j]: j>>1 = k2-row t (0..3), j&1 = col quad (c0..3 / c0+4..7)
    uint4 wc[8], wn[8];
#pragma unroll
    for (int j = 0; j < 8; ++j)
        wc[j] = *reinterpret_cast<const uint4*>(wtv + (j >> 1) * DM + c0 + (j & 1) * 4);

#pragma unroll
    for (int k8 = 0; k8 < NK8; ++k8) {
        if (k8 + 1 < NK8) {
            const unsigned* wnp = wtv + (size_t)(k8 + 1) * 4 * DM;
#pragma unroll
            for (int j = 0; j < 8; ++j)
                wn[j] = *reinterpret_cast<const uint4*>(wnp + (j >> 1) * DM + c0 + (j & 1) * 4);
        }
#pragma unroll
        for (int rp = 0; rp < 4; ++rp) {
            uint4 pa = *reinterpret_cast<const uint4*>(prow + (2 * rp)     * PL2 + k8 * 4);
            uint4 pb = *reinterpret_cast<const uint4*>(prow + (2 * rp + 1) * PL2 + k8 * 4);
#pragma unroll
            for (int t = 0; t < 4; ++t) {
                unsigned ua = (t == 0) ? pa.x : (t == 1) ? pa.y : (t == 2) ? pa.z : pa.w;
                unsigned ub = (t == 0) ? pb.x : (t == 1) ? pb.y : (t == 2) ? pb.z : pb.w;
                h2 qa = bch2(ua), qb = bch2(ub);
                uint4 wA = wc[2 * t], wB = wc[2 * t + 1];
                acc[2*rp][0] = fdot2f(qa, bch2(wA.x), acc[2*rp][0]);
                acc[2*rp][1] = fdot2f(qa, bch2(wA.y), acc[2*rp][1]);
                acc[2*rp][2] = fdot2f(qa, bch2(wA.z), acc[2*rp][2]);
                acc[2*rp][3] = fdot2f(qa, bch2(wA.w), acc[2*rp][3]);
                acc[2*rp][4] = fdot2f(qa, bch2(wB.x), acc[2*rp][4]);
                acc[2*rp][5] = fdot2f(qa, bch2(wB.y), acc[2*rp][5]);
                acc[2*rp][6] = fdot2f(qa, bch2(wB.z), acc[2*rp][6]);
                acc[2*rp][7] = fdot2f(qa, bch2(wB.w), acc[2*rp][7]);
                acc[2*rp+1][0] = fdot2f(qb, bch2(wA.x), acc[2*rp+1][0]);
                acc[2*rp+1][1] = fdot2f(qb, bch2(wA.y), acc[2*rp+1][1]);
                acc[2*rp+1][2] = fdot2f(qb, bch2(wA.z), acc[2*rp+1][2]);
                acc[2*rp+1][3] = fdot2f(qb, bch2(wA.w), acc[2*rp+1][3]);
                acc[2*rp+1][4] = fdot2f(qb, bch2(wB.x), acc[2*rp+1][4]);
                acc[2*rp+1][5] = fdot2f(qb, bch2(wB.y), acc[2*rp+1][5]);
                acc[2*rp+1][6] = fdot2f(qb, bch2(wB.z), acc[2*rp+1][6]);
                acc[2*rp+1][7] = fdot2f(qb, bch2(wB.w), acc[2*rp+1][7]);
            }
        }
        if (k8 + 1 < NK8) {
#pragma unroll
            for (int j = 0; j < 8; ++j) wc[j] = wn[j];
        }
    }

    // ---- fp32 epilogue: + bias + channel + pe, nontemporal float4 stores ----
    float4 bcA, bcB;
    {
        float4 ba = *reinterpret_cast<const float4*>(bias + c0);
        float4 bb = *reinterpret_cast<const float4*>(bias + c0 + 4);
        float4 ca = *reinterpret_cast<const float4*>(chan + v * DM + c0);
        float4 cb = *reinterpret_cast<const float4*>(chan + v * DM + c0 + 4);
        bcA.x = ba.x + ca.x; bcA.y = ba.y + ca.y; bcA.z = ba.z + ca.z; bcA.w = ba.w + ca.w;
        bcB.x = bb.x + cb.x; bcB.y = bb.y + cb.y; bcB.z = bb.z + cb.z; bcB.w = bb.w + cb.w;
    }

    const int row0 = i0 + wv * 8;
    float* ob = out + ((size_t)(b * TOK + tokoff + row0)) * DM + c0;
    const float* pb = ws /*pe*/ + (size_t)row0 * DM + c0;
#pragma unroll
    for (int r = 0; r < 8; ++r) {
        float4 pA = *reinterpret_cast<const float4*>(pb + (size_t)r * DM);
        float4 pB = *reinterpret_cast<const float4*>(pb + (size_t)r * DM + 4);
        float4 oA, oB;
        oA.x = acc[r][0] + bcA.x + pA.x;
        oA.y = acc[r][1] + bcA.y + pA.y;
        oA.z = acc[r][2] + bcA.z + pA.z;
        oA.w = acc[r][3] + bcA.w + pA.w;
        oB.x = acc[r][4] + bcB.x + pB.x;
        oB.y = acc[r][5] + bcB.y + pB.y;
        oB.z = acc[r][6] + bcB.z + pB.z;
        oB.w = acc[r][7] + bcB.w + pB.w;
        nt_store4(ob + (size_t)r * DM,     oA);
        nt_store4(ob + (size_t)r * DM + 4, oB);
    }
}

// ---------------------------------------------------------------------------
// Main kernel. Blocks [0,1600): 32 rows x 512 cols. [1600,1608): global toks.
// ---------------------------------------------------------------------------
__global__ __launch_bounds__(NTHR, 3) void patch_embed_kernel(
    const float* __restrict__ x,
    const float* __restrict__ b16,  const float* __restrict__ b32,
    const float* __restrict__ b64,  const float* __restrict__ b128,
    const float* __restrict__ glb,  const float* __restrict__ chan,
    const float* __restrict__ ws,   float* __restrict__ out)
{
    extern __shared__ float ldsf[];              // 32 rows * pl/2 half2 words, <= 8 KB
    unsigned* ldsu = reinterpret_cast<unsigned*>(ldsf);
    int bid = blockIdx.x;
    const int tid = threadIdx.x;

    if (bid >= 1600) {                           // global-token rows (8 blocks)
        int v = bid - 1600;
        int d2 = tid << 1;
        float2 g = *reinterpret_cast<const float2*>(glb + d2);
        float2 c = *reinterpret_cast<const float2*>(chan + v * DM + d2);
        float2 o; o.x = g.x + c.x; o.y = g.y + c.y;
        int row0 = c_tokoff[v] + c_np[v];
        for (int b = 0; b < 32; ++b)
            *reinterpret_cast<float2*>(out + ((size_t)(b * TOK + row0)) * DM + d2) = o;
        return;
    }

    // ---- block -> (v, b, chunk), block-uniform scalar work ----
    int seg = 0;
    while (bid >= c_cum[seg + 1]) ++seg;
    int local = bid - c_cum[seg];
    int v = c_segv[seg];
    int lg = c_lgch[seg];
    int b = local >> lg;
    int chunk = local & ((1 << lg) - 1);
    int i0 = chunk * BROWS;
    int tokoff = c_tokoff[v];

    switch (v) {
        case 0: patch_block<16, 1>(x, ldsu, b16,  chan, ws, out, 0, b, i0, tokoff); break;
        case 1: patch_block<16, 1>(x, ldsu, b16,  chan, ws, out, 1, b, i0, tokoff); break;
        case 2: patch_block<32, 2>(x, ldsu, b32,  chan, ws, out, 2, b, i0, tokoff); break;
        case 3: patch_block<32, 2>(x, ldsu, b32,  chan, ws, out, 3, b, i0, tokoff); break;
        case 4: patch_block<64, 1>(x, ldsu, b64,  chan, ws, out, 4, b, i0, tokoff); break;
        case 5: patch_block<64, 1>(x, ldsu, b64,  chan, ws, out, 5, b, i0, tokoff); break;
        case 6: patch_block<128,2>(x, ldsu, b128, chan, ws, out, 6, b, i0, tokoff); break;
        case 7: patch_block<128,2>(x, ldsu, b128, chan, ws, out, 7, b, i0, tokoff); break;
    }
}

extern "C" void kernel_launch(void* const* d_in, const int* in_sizes, int n_in,
                              void* d_out, int out_size, void* d_ws, size_t ws_size,
                              hipStream_t stream) {
    const float* x    = (const float*)d_in[0];
    const float* w16  = (const float*)d_in[1];
    const float* b16  = (const float*)d_in[2];
    const float* w32  = (const float*)d_in[3];
    const float* b32  = (const float*)d_in[4];
    const float* w64  = (const float*)d_in[5];
    const float* b64  = (const float*)d_in[6];
    const float* w128 = (const float*)d_in[7];
    const float* b128 = (const float*)d_in[8];
    const float* glb  = (const float*)d_in[9];
    const float* chan = (const float*)d_in[10];
    float* out = (float*)d_out;
    float* ws  = (float*)d_ws;   // pe fp32 [0,262144) + packed fp16 wt -> 1.29 MB

    hipLaunchKernelGGL(setup_kernel, dim3(632), dim3(512), 0, stream,
                       w16, w32, w64, w128, ws);
    hipLaunchKernelGGL(patch_embed_kernel, dim3(1608), dim3(NTHR),
                       BROWS * 64 * sizeof(unsigned),   // 8 KB dynamic LDS (pl=128)
                       stream,
                       x, b16, b32, b64, b128, glb, chan, ws, out);
}

// Round 9
// 57.783 us; speedup vs baseline: 1.4927x; 1.4927x over previous
//
#include <hip/hip_runtime.h>
#include <math.h>

#define DM 512
#define LSEQ 8192
#define NV 8
#define TOK 1608
#define BROWS 16     // patch rows per block
#define NTHR 256     // 4 waves; wave = 4 rows x 512 cols; thread = 4r x 8c

typedef _Float16 h2 __attribute__((ext_vector_type(2)));
typedef float f4n __attribute__((ext_vector_type(4)));   // native float4 for builtins

// Heavy-first segment order (pl=128 first). seg -> v: {6,7,4,5,2,3,0,1}
__device__ __constant__ int c_segv[8]   = {6, 7, 4, 5, 2, 3, 0, 1};
// 16-row blocks per seg = 32 batches * (n_p/16): 64,64,256,256,256,256,1024,1024
__device__ __constant__ int c_cum[9]    = {0, 64, 128, 384, 640, 896, 1152, 2176, 3200};
__device__ __constant__ int c_lgch[8]   = {1, 1, 3, 3, 3, 3, 5, 5};   // log2(chunks/batch)
// indexed by v:
__device__ __constant__ int c_tokoff[8] = {0, 513, 1026, 1155, 1284, 1413, 1542, 1575};
__device__ __constant__ int c_np[8]     = {512, 512, 128, 128, 128, 128, 32, 32};
__device__ __constant__ int c_pl[8]     = {16, 16, 32, 32, 64, 64, 128, 128};
__device__ __constant__ int c_sf[8]     = {1, 1, 2, 2, 1, 1, 2, 2};
// packed-half2-weight word offsets within d_ws per v; pe occupies words [0,262144)
__device__ __constant__ int c_wtoff[8]  = {262144, 262144, 266240, 266240,
                                           274432, 274432, 290816, 290816};

__device__ __forceinline__ float fdot2f(h2 a, h2 b, float c) {
#if __has_builtin(__builtin_amdgcn_fdot2)
    return __builtin_amdgcn_fdot2(a, b, c, false);
#else
    return fmaf((float)a.y, (float)b.y, fmaf((float)a.x, (float)b.x, c));
#endif
}
__device__ __forceinline__ h2 bch2(unsigned u) { return __builtin_bit_cast(h2, u); }

__device__ __forceinline__ void nt_store4(float* p, float4 v) {
#if __has_builtin(__builtin_nontemporal_store)
    f4n t; t.x = v.x; t.y = v.y; t.z = v.z; t.w = v.w;
    __builtin_nontemporal_store(t, reinterpret_cast<f4n*>(p));
#else
    *reinterpret_cast<float4*>(p) = v;
#endif
}

// ---------------------------------------------------------------------------
// Setup: blocks [0,512) build pe[512][512] fp32 (numpy-matched sinusoidal);
// blocks [512,632) pack transposed fp16 weights wt_h[k2][512] (half2 words).
// ---------------------------------------------------------------------------
__global__ __launch_bounds__(512) void setup_kernel(
    const float* __restrict__ w16, const float* __restrict__ w32,
    const float* __restrict__ w64, const float* __restrict__ w128,
    float* __restrict__ ws)
{
    int bid = blockIdx.x;
    int d = threadIdx.x;
    if (bid < 512) {
        int idx = bid * 512 + d;
        int i = idx >> 9;
        int dd = idx & (DM - 1);
        const float c = -9.210340371976184f / 512.0f;  // -ln(10000)/D
        float div = expf((float)(dd & ~1) * c);
        float ang = (float)i * div;
        ws[idx] = (dd & 1) ? cosf(ang) : sinf(ang);
        return;
    }
    int j = bid - 512;                 // 120 half2-rows across the 4 matrices
    const float* w; int pl, k2, off;
    if (j < 8)       { w = w16;  pl = 16;  k2 = j;      off = 262144; }
    else if (j < 24) { w = w32;  pl = 32;  k2 = j - 8;  off = 266240; }
    else if (j < 56) { w = w64;  pl = 64;  k2 = j - 24; off = 274432; }
    else             { w = w128; pl = 128; k2 = j - 56; off = 290816; }
    float2 p = *reinterpret_cast<const float2*>(w + (size_t)d * pl + 2 * k2);
    h2 h; h.x = (_Float16)p.x; h.y = (_Float16)p.y;
    reinterpret_cast<unsigned*>(ws)[off + k2 * DM + d] = __builtin_bit_cast(unsigned, h);
}

// 8-col dot update for one row r with patch half2 P and W quads X (cols 0-3),
// Y (cols 4-7)
#define DOT8(r, P, X, Y)                                        \
    acc[r][0] = fdot2f(P, bch2((X).x), acc[r][0]);              \
    acc[r][1] = fdot2f(P, bch2((X).y), acc[r][1]);              \
    acc[r][2] = fdot2f(P, bch2((X).z), acc[r][2]);              \
    acc[r][3] = fdot2f(P, bch2((X).w), acc[r][3]);              \
    acc[r][4] = fdot2f(P, bch2((Y).x), acc[r][4]);              \
    acc[r][5] = fdot2f(P, bch2((Y).y), acc[r][5]);              \
    acc[r][6] = fdot2f(P, bch2((Y).z), acc[r][6]);              \
    acc[r][7] = fdot2f(P, bch2((Y).w), acc[r][7]);

// ---------------------------------------------------------------------------
// Main kernel. Blocks [0,3200): 16 rows x 512 cols; thread = 4 rows x 8 cols,
// fp16 dot2, fp32 epilogue. Blocks [3200,3208): global-token rows.
// ---------------------------------------------------------------------------
__global__ __launch_bounds__(NTHR, 4) void patch_embed_kernel(
    const float* __restrict__ x,
    const float* __restrict__ b16,  const float* __restrict__ b32,
    const float* __restrict__ b64,  const float* __restrict__ b128,
    const float* __restrict__ glb,  const float* __restrict__ chan,
    const float* __restrict__ ws,   float* __restrict__ out)
{
    extern __shared__ float ldsf[];              // 16 rows * pl/2 half2 words, <= 4 KB
    unsigned* ldsu = reinterpret_cast<unsigned*>(ldsf);
    int bid = blockIdx.x;
    const int tid = threadIdx.x;

    if (bid >= 3200) {                           // global-token rows (8 blocks)
        int v = bid - 3200;
        int d2 = tid << 1;
        float2 g = *reinterpret_cast<const float2*>(glb + d2);
        float2 c = *reinterpret_cast<const float2*>(chan + v * DM + d2);
        float2 o; o.x = g.x + c.x; o.y = g.y + c.y;
        int row0 = c_tokoff[v] + c_np[v];
        for (int b = 0; b < 32; ++b)
            *reinterpret_cast<float2*>(out + ((size_t)(b * TOK + row0)) * DM + d2) = o;
        return;
    }

    // ---- block -> (v, b, chunk), block-uniform scalar work ----
    int seg = 0;
    while (bid >= c_cum[seg + 1]) ++seg;
    int local = bid - c_cum[seg];
    int v = c_segv[seg];
    int lg = c_lgch[seg];
    int b = local >> lg;
    int chunk = local & ((1 << lg) - 1);
    const int pl = c_pl[v];
    const int sf = c_sf[v];
    const int pl2 = pl >> 1;
    const int i0 = chunk * BROWS;

    // ---- stage 16 packed patches into LDS as half2 (sampling folded) ----
    const int ne2 = (BROWS * pl) >> 1;           // half2 words
    const float* xb = x + ((size_t)b * NV + v) * LSEQ + (size_t)i0 * (pl * sf);
    if (sf == 1) {
        for (int t = tid; t < (ne2 >> 1); t += NTHR) {   // t = one float4 = 2 words
            float4 q = *reinterpret_cast<const float4*>(xb + 4 * t);
            h2 a; a.x = (_Float16)q.x; a.y = (_Float16)q.y;
            h2 c; c.x = (_Float16)q.z; c.y = (_Float16)q.w;
            uint2 o; o.x = __builtin_bit_cast(unsigned, a);
            o.y = __builtin_bit_cast(unsigned, c);
            *reinterpret_cast<uint2*>(ldsu + 2 * t) = o;
        }
    } else {
        for (int p = tid; p < ne2; p += NTHR) {          // one word per float4
            float4 q = *reinterpret_cast<const float4*>(xb + 4 * p);
            h2 a; a.x = (_Float16)q.x; a.y = (_Float16)q.z;
            ldsu[p] = __builtin_bit_cast(unsigned, a);
        }
    }
    __syncthreads();

    // ---- per-thread geometry ----
    const int lane = tid & 63;
    const int wv   = tid >> 6;                   // wave -> rows [4wv, 4wv+4)
    const int c0   = lane << 3;                  // 8 consecutive cols
    const unsigned* prow = ldsu + (wv * 4) * pl2;
    const unsigned* wtv  = reinterpret_cast<const unsigned*>(ws) + c_wtoff[v];

    float acc[4][8];
#pragma unroll
    for (int r = 0; r < 4; ++r)
#pragma unroll
        for (int c = 0; c < 8; ++c) acc[r][c] = 0.f;

    // ---- K loop: 8 k per iter, two 4-k halves; W slots ping-pong (A/B),
    //      each slot = 2 k2-rows x 2 col-quads = 16 VGPR. ----
    uint4 aX0 = *reinterpret_cast<const uint4*>(wtv + c0);
    uint4 aY0 = *reinterpret_cast<const uint4*>(wtv + c0 + 4);
    uint4 aX1 = *reinterpret_cast<const uint4*>(wtv + DM + c0);
    uint4 aY1 = *reinterpret_cast<const uint4*>(wtv + DM + c0 + 4);

    for (int k4 = 0; k4 < pl2; k4 += 4) {
        // slot B <- W(k4+2), W(k4+3)   (always in range; pl2 % 4 == 0)
        const unsigned* wb_ = wtv + (size_t)(k4 + 2) * DM;
        uint4 bX0 = *reinterpret_cast<const uint4*>(wb_ + c0);
        uint4 bY0 = *reinterpret_cast<const uint4*>(wb_ + c0 + 4);
        uint4 bX1 = *reinterpret_cast<const uint4*>(wb_ + DM + c0);
        uint4 bY1 = *reinterpret_cast<const uint4*>(wb_ + DM + c0 + 4);

        // patch quads: 4 rows x 4 k2 (8 k) broadcast b128 reads
        uint4 pr0 = *reinterpret_cast<const uint4*>(prow + 0 * pl2 + k4);
        uint4 pr1 = *reinterpret_cast<const uint4*>(prow + 1 * pl2 + k4);
        uint4 pr2 = *reinterpret_cast<const uint4*>(prow + 2 * pl2 + k4);
        uint4 pr3 = *reinterpret_cast<const uint4*>(prow + 3 * pl2 + k4);

        // half A: k2 = k4, k4+1 with slot A
        DOT8(0, bch2(pr0.x), aX0, aY0)  DOT8(0, bch2(pr0.y), aX1, aY1)
        DOT8(1, bch2(pr1.x), aX0, aY0)  DOT8(1, bch2(pr1.y), aX1, aY1)
        DOT8(2, bch2(pr2.x), aX0, aY0)  DOT8(2, bch2(pr2.y), aX1, aY1)
        DOT8(3, bch2(pr3.x), aX0, aY0)  DOT8(3, bch2(pr3.y), aX1, aY1)

        // slot A <- W(k4+4), W(k4+5) for next iteration
        if (k4 + 4 < pl2) {
            const unsigned* wa_ = wtv + (size_t)(k4 + 4) * DM;
            aX0 = *reinterpret_cast<const uint4*>(wa_ + c0);
            aY0 = *reinterpret_cast<const uint4*>(wa_ + c0 + 4);
            aX1 = *reinterpret_cast<const uint4*>(wa_ + DM + c0);
            aY1 = *reinterpret_cast<const uint4*>(wa_ + DM + c0 + 4);
        }

        // half B: k2 = k4+2, k4+3 with slot B
        DOT8(0, bch2(pr0.z), bX0, bY0)  DOT8(0, bch2(pr0.w), bX1, bY1)
        DOT8(1, bch2(pr1.z), bX0, bY0)  DOT8(1, bch2(pr1.w), bX1, bY1)
        DOT8(2, bch2(pr2.z), bX0, bY0)  DOT8(2, bch2(pr2.w), bX1, bY1)
        DOT8(3, bch2(pr3.z), bX0, bY0)  DOT8(3, bch2(pr3.w), bX1, bY1)
    }

    // ---- fp32 epilogue: + bias + channel + pe, nontemporal float4 stores ----
    const float* bias = (pl == 16) ? b16 : (pl == 32) ? b32 : (pl == 64) ? b64 : b128;
    float4 bcA, bcB;
    {
        float4 ba = *reinterpret_cast<const float4*>(bias + c0);
        float4 bb = *reinterpret_cast<const float4*>(bias + c0 + 4);
        float4 ca = *reinterpret_cast<const float4*>(chan + v * DM + c0);
        float4 cb = *reinterpret_cast<const float4*>(chan + v * DM + c0 + 4);
        bcA.x = ba.x + ca.x; bcA.y = ba.y + ca.y; bcA.z = ba.z + ca.z; bcA.w = ba.w + ca.w;
        bcB.x = bb.x + cb.x; bcB.y = bb.y + cb.y; bcB.z = bb.z + cb.z; bcB.w = bb.w + cb.w;
    }

    const int row0 = i0 + wv * 4;
    float* ob = out + ((size_t)(b * TOK + c_tokoff[v] + row0)) * DM + c0;
    const float* pb = ws /*pe*/ + (size_t)row0 * DM + c0;
#pragma unroll
    for (int r = 0; r < 4; ++r) {
        float4 pA = *reinterpret_cast<const float4*>(pb + (size_t)r * DM);
        float4 pB = *reinterpret_cast<const float4*>(pb + (size_t)r * DM + 4);
        float4 oA, oB;
        oA.x = acc[r][0] + bcA.x + pA.x;
        oA.y = acc[r][1] + bcA.y + pA.y;
        oA.z = acc[r][2] + bcA.z + pA.z;
        oA.w = acc[r][3] + bcA.w + pA.w;
        oB.x = acc[r][4] + bcB.x + pB.x;
        oB.y = acc[r][5] + bcB.y + pB.y;
        oB.z = acc[r][6] + bcB.z + pB.z;
        oB.w = acc[r][7] + bcB.w + pB.w;
        nt_store4(ob + (size_t)r * DM,     oA);
        nt_store4(ob + (size_t)r * DM + 4, oB);
    }
}

extern "C" void kernel_launch(void* const* d_in, const int* in_sizes, int n_in,
                              void* d_out, int out_size, void* d_ws, size_t ws_size,
                              hipStream_t stream) {
    const float* x    = (const float*)d_in[0];
    const float* w16  = (const float*)d_in[1];
    const float* b16  = (const float*)d_in[2];
    const float* w32  = (const float*)d_in[3];
    const float* b32  = (const float*)d_in[4];
    const float* w64  = (const float*)d_in[5];
    const float* b64  = (const float*)d_in[6];
    const float* w128 = (const float*)d_in[7];
    const float* b128 = (const float*)d_in[8];
    const float* glb  = (const float*)d_in[9];
    const float* chan = (const float*)d_in[10];
    float* out = (float*)d_out;
    float* ws  = (float*)d_ws;   // pe fp32 [0,262144) + packed fp16 wt -> 1.29 MB

    hipLaunchKernelGGL(setup_kernel, dim3(632), dim3(512), 0, stream,
                       w16, w32, w64, w128, ws);
    hipLaunchKernelGGL(patch_embed_kernel, dim3(3208), dim3(NTHR),
                       BROWS * 64 * sizeof(unsigned),   // 4 KB dynamic LDS (pl=128)
                       stream,
                       x, b16, b32, b64, b128, glb, chan, ws, out);
}